// Round 4
// baseline (382.952 us; speedup 1.0000x reference)
//
#include <hip/hip_runtime.h>
#include <math.h>

#define VOCAB 50257
#define DIM 768
#define RANK 16
#define SCALING 2.0f   // ALPHA / RANK = 32/16

constexpr int P1_BLOCKS = 1024;
constexpr int P1_THREADS = 192;                                      // 3 waves; thread owns 4 cols
constexpr int ROWS_PB = (VOCAB + P1_BLOCKS - 1) / P1_BLOCKS;         // 50

constexpr int TOK_PB = 8;
constexpr int G_THREADS = 192;

// ws layout (bytes): [0,3072) sumsq[768] (memset 0) | [3072,3076) counter (memset 0)
//                    [3088,6160) scale[768] (16B-aligned for float4 reads)
constexpr size_t WS_SUMSQ_OFF = 0;
constexpr size_t WS_COUNTER_OFF = 3072;
constexpr size_t WS_SCALE_OFF = 3088;

// ---- K1: column sum-of-squares via device-scope atomics; last-finishing block
//      computes scale[c] = mag[c]/max(norm,1e-8). Deadlock-free (no spin). ----
__global__ __launch_bounds__(P1_THREADS) void dora_pass1(
    const float* __restrict__ emb, const float* __restrict__ lora_a,
    const float* __restrict__ lora_b, const float* __restrict__ magnitude,
    float* __restrict__ sumsq, float* __restrict__ scale,
    unsigned* __restrict__ counter) {
  const int t = threadIdx.x;
  const int c4 = t * 4;

  float4 B[RANK];  // B[:, c4..c4+3], reused across all rows
#pragma unroll
  for (int k = 0; k < RANK; ++k)
    B[k] = *reinterpret_cast<const float4*>(lora_b + k * DIM + c4);

  const int r0 = blockIdx.x * ROWS_PB;
  const int r1 = min(r0 + ROWS_PB, VOCAB);
  float4 acc = make_float4(0.f, 0.f, 0.f, 0.f);
#pragma unroll 2
  for (int v = r0; v < r1; ++v) {
    const float4 e = *reinterpret_cast<const float4*>(emb + (size_t)v * DIM + c4);
    float dx = 0.f, dy = 0.f, dz = 0.f, dw = 0.f;
#pragma unroll
    for (int k = 0; k < RANK; ++k) {
      const float a = lora_a[(size_t)v * RANK + k];   // block-uniform -> scalar loads
      dx = fmaf(a, B[k].x, dx);
      dy = fmaf(a, B[k].y, dy);
      dz = fmaf(a, B[k].z, dz);
      dw = fmaf(a, B[k].w, dw);
    }
    const float cx = fmaf(SCALING, dx, e.x);
    const float cy = fmaf(SCALING, dy, e.y);
    const float cz = fmaf(SCALING, dz, e.z);
    const float cw = fmaf(SCALING, dw, e.w);
    acc.x = fmaf(cx, cx, acc.x);
    acc.y = fmaf(cy, cy, acc.y);
    acc.z = fmaf(cz, cz, acc.z);
    acc.w = fmaf(cw, cw, acc.w);
  }
  // device-scope by default on global memory [learn_hip m20]
  atomicAdd(&sumsq[c4 + 0], acc.x);
  atomicAdd(&sumsq[c4 + 1], acc.y);
  atomicAdd(&sumsq[c4 + 2], acc.z);
  atomicAdd(&sumsq[c4 + 3], acc.w);

  __threadfence();        // release: our sumsq atomics ordered before counter bump
  __syncthreads();        // all 192 threads' atomics issued+drained before t0 signals
  __shared__ unsigned is_last;
  if (t == 0) is_last = (atomicAdd(counter, 1u) == P1_BLOCKS - 1) ? 1u : 0u;
  __syncthreads();
  if (is_last) {
    // last FINISHING block: every other block's sumsq atomics are complete.
    // Read via device-scope RMW (atomicAdd 0) to bypass any stale cache line.
    const float sx = atomicAdd(&sumsq[c4 + 0], 0.0f);
    const float sy = atomicAdd(&sumsq[c4 + 1], 0.0f);
    const float sz = atomicAdd(&sumsq[c4 + 2], 0.0f);
    const float sw = atomicAdd(&sumsq[c4 + 3], 0.0f);
    float4 sc;
    sc.x = magnitude[c4 + 0] / fmaxf(sqrtf(sx), 1e-8f);
    sc.y = magnitude[c4 + 1] / fmaxf(sqrtf(sy), 1e-8f);
    sc.z = magnitude[c4 + 2] / fmaxf(sqrtf(sz), 1e-8f);
    sc.w = magnitude[c4 + 3] / fmaxf(sqrtf(sw), 1e-8f);
    *reinterpret_cast<float4*>(scale + c4) = sc;
    // visibility to K2 guaranteed by kernel-boundary release/acquire
  }
}

// ---- K2: gather 8 tokens/block; B + scale in registers; E rows L3-resident ----
__global__ __launch_bounds__(G_THREADS) void dora_gather(
    const int* __restrict__ tokens, const float* __restrict__ emb,
    const float* __restrict__ lora_a, const float* __restrict__ lora_b,
    const float* __restrict__ scale, float* __restrict__ out, int n_tokens) {
  const int t = threadIdx.x;
  const int c4 = t * 4;

  float4 B[RANK];
#pragma unroll
  for (int k = 0; k < RANK; ++k)
    B[k] = *reinterpret_cast<const float4*>(lora_b + k * DIM + c4);
  const float4 sc = *reinterpret_cast<const float4*>(scale + c4);

  const int tok0 = blockIdx.x * TOK_PB;
#pragma unroll
  for (int i = 0; i < TOK_PB; ++i) {
    const int tok = tok0 + i;
    if (tok >= n_tokens) break;
    const int id = tokens[tok];                                   // block-uniform
    const float* __restrict__ arow = lora_a + (size_t)id * RANK;  // scalar loads
    const float4 e = *reinterpret_cast<const float4*>(emb + (size_t)id * DIM + c4);
    float dx = 0.f, dy = 0.f, dz = 0.f, dw = 0.f;
#pragma unroll
    for (int k = 0; k < RANK; ++k) {
      const float a = arow[k];
      dx = fmaf(a, B[k].x, dx);
      dy = fmaf(a, B[k].y, dy);
      dz = fmaf(a, B[k].z, dz);
      dw = fmaf(a, B[k].w, dw);
    }
    float4 o;
    o.x = fmaf(SCALING, dx, e.x) * sc.x;
    o.y = fmaf(SCALING, dy, e.y) * sc.y;
    o.z = fmaf(SCALING, dz, e.z) * sc.z;
    o.w = fmaf(SCALING, dw, e.w) * sc.w;
    *reinterpret_cast<float4*>(out + (size_t)tok * DIM + c4) = o;
  }
}

extern "C" void kernel_launch(void* const* d_in, const int* in_sizes, int n_in,
                              void* d_out, int out_size, void* d_ws, size_t ws_size,
                              hipStream_t stream) {
  const int*   tokens    = (const int*)d_in[0];    // [8,2048] int32
  const float* emb       = (const float*)d_in[1];  // [V, D]
  const float* lora_a    = (const float*)d_in[2];  // [V, R]
  const float* lora_b    = (const float*)d_in[3];  // [R, D]
  const float* magnitude = (const float*)d_in[4];  // [D]
  float* out = (float*)d_out;

  const int n_tokens = in_sizes[0];                // 16384

  char* ws = (char*)d_ws;
  float*    sumsq   = (float*)(ws + WS_SUMSQ_OFF);
  unsigned* counter = (unsigned*)(ws + WS_COUNTER_OFF);
  float*    scale   = (float*)(ws + WS_SCALE_OFF);

  // ws is re-poisoned to 0xAA before every timed call: zero sumsq+counter each call.
  hipMemsetAsync(ws, 0, WS_COUNTER_OFF + 4, stream);

  dora_pass1<<<P1_BLOCKS, P1_THREADS, 0, stream>>>(emb, lora_a, lora_b, magnitude,
                                                   sumsq, scale, counter);

  const int gather_blocks = (n_tokens + TOK_PB - 1) / TOK_PB;
  dora_gather<<<gather_blocks, G_THREADS, 0, stream>>>(tokens, emb, lora_a, lora_b,
                                                       scale, out, n_tokens);
}

// Round 5
// 283.498 us; speedup vs baseline: 1.3508x; 1.3508x over previous
//
#include <hip/hip_runtime.h>
#include <math.h>

#define VOCAB 50257
#define DIM 768
#define RANK 16
#define SCALING 2.0f   // ALPHA / RANK = 32/16

constexpr int P1_BLOCKS = 1024;
constexpr int P1_THREADS = 192;                                      // 3 waves; thread owns 4 cols
constexpr int ROWS_PB = (VOCAB + P1_BLOCKS - 1) / P1_BLOCKS;         // 50

constexpr int RED_THREADS = 1024;
constexpr int RED_WAVES = RED_THREADS / 64;   // 16
constexpr int RED_BLOCKS = DIM / 64;          // 12 blocks x 64 columns

constexpr int TOK_PB = 8;
constexpr int G_THREADS = 192;

// Opaque register pin: result of empty asm cannot be rematerialized as a re-load,
// so B stays in VGPRs across the row loop (R4 showed VGPR_Count=48 -> compiler was
// re-fetching the 49 KB B matrix from L1/L2 every iteration; ~70 us of L2 traffic).
#define PIN4(f4) asm volatile("" : "+v"((f4).x), "+v"((f4).y), "+v"((f4).z), "+v"((f4).w))

// ---------------- K1: per-block partial column sum-of-squares ----------------
// partials[P1_BLOCKS][DIM] row-major; every slot written -> no ws zero-init needed.
__global__ __launch_bounds__(P1_THREADS) void dora_pass1(
    const float* __restrict__ emb, const float* __restrict__ lora_a,
    const float* __restrict__ lora_b, float* __restrict__ partials) {
  const int t = threadIdx.x;
  const int c4 = t * 4;

  float4 B[RANK];  // B[:, c4..c4+3] — 64 VGPRs, pinned resident
#pragma unroll
  for (int k = 0; k < RANK; ++k) {
    B[k] = *reinterpret_cast<const float4*>(lora_b + k * DIM + c4);
    PIN4(B[k]);
  }

  const int r0 = blockIdx.x * ROWS_PB;
  const int r1 = min(r0 + ROWS_PB, VOCAB);
  float4 acc = make_float4(0.f, 0.f, 0.f, 0.f);
#pragma unroll 4
  for (int v = r0; v < r1; ++v) {
    const float4 e = *reinterpret_cast<const float4*>(emb + (size_t)v * DIM + c4);
    float dx = 0.f, dy = 0.f, dz = 0.f, dw = 0.f;
#pragma unroll
    for (int k = 0; k < RANK; ++k) {
      const float a = lora_a[(size_t)v * RANK + k];   // block-uniform -> scalar loads
      dx = fmaf(a, B[k].x, dx);
      dy = fmaf(a, B[k].y, dy);
      dz = fmaf(a, B[k].z, dz);
      dw = fmaf(a, B[k].w, dw);
    }
    const float cx = fmaf(SCALING, dx, e.x);
    const float cy = fmaf(SCALING, dy, e.y);
    const float cz = fmaf(SCALING, dz, e.z);
    const float cw = fmaf(SCALING, dw, e.w);
    acc.x = fmaf(cx, cx, acc.x);
    acc.y = fmaf(cy, cy, acc.y);
    acc.z = fmaf(cz, cz, acc.z);
    acc.w = fmaf(cw, cw, acc.w);
  }
  *reinterpret_cast<float4*>(partials + (size_t)blockIdx.x * DIM + c4) = acc;
}

// ---------------- K2: reduce, block owns 64 consecutive columns (coalesced) ----------------
__global__ __launch_bounds__(RED_THREADS) void dora_reduce(
    const float* __restrict__ partials, const float* __restrict__ magnitude,
    float* __restrict__ scale) {
  const int lane = threadIdx.x & 63;
  const int w = threadIdx.x >> 6;            // 0..15
  const int c = blockIdx.x * 64 + lane;      // consecutive lanes -> consecutive columns

  float s = 0.f;
#pragma unroll 8
  for (int r = w; r < P1_BLOCKS; r += RED_WAVES)   // 256 B contiguous per wave-load
    s += partials[(size_t)r * DIM + c];

  __shared__ float lds[RED_WAVES][64];
  lds[w][lane] = s;
  __syncthreads();
  if (w == 0) {
    float tot = 0.f;
#pragma unroll
    for (int i = 0; i < RED_WAVES; ++i) tot += lds[i][lane];
    scale[c] = magnitude[c] / fmaxf(sqrtf(tot), 1e-8f);
  }
}

// ---------------- K3: gather, 8 tokens/block; B + scale pinned in registers ----------------
__global__ __launch_bounds__(G_THREADS) void dora_gather(
    const int* __restrict__ tokens, const float* __restrict__ emb,
    const float* __restrict__ lora_a, const float* __restrict__ lora_b,
    const float* __restrict__ scale, float* __restrict__ out, int n_tokens) {
  const int t = threadIdx.x;
  const int c4 = t * 4;

  float4 B[RANK];
#pragma unroll
  for (int k = 0; k < RANK; ++k) {
    B[k] = *reinterpret_cast<const float4*>(lora_b + k * DIM + c4);
    PIN4(B[k]);
  }
  float4 sc = *reinterpret_cast<const float4*>(scale + c4);
  PIN4(sc);

  const int tok0 = blockIdx.x * TOK_PB;
#pragma unroll
  for (int i = 0; i < TOK_PB; ++i) {
    const int tok = tok0 + i;
    if (tok >= n_tokens) break;
    const int id = tokens[tok];                                   // block-uniform
    const float* __restrict__ arow = lora_a + (size_t)id * RANK;  // scalar loads
    const float4 e = *reinterpret_cast<const float4*>(emb + (size_t)id * DIM + c4);
    float dx = 0.f, dy = 0.f, dz = 0.f, dw = 0.f;
#pragma unroll
    for (int k = 0; k < RANK; ++k) {
      const float a = arow[k];
      dx = fmaf(a, B[k].x, dx);
      dy = fmaf(a, B[k].y, dy);
      dz = fmaf(a, B[k].z, dz);
      dw = fmaf(a, B[k].w, dw);
    }
    float4 o;
    o.x = fmaf(SCALING, dx, e.x) * sc.x;
    o.y = fmaf(SCALING, dy, e.y) * sc.y;
    o.z = fmaf(SCALING, dz, e.z) * sc.z;
    o.w = fmaf(SCALING, dw, e.w) * sc.w;
    *reinterpret_cast<float4*>(out + (size_t)tok * DIM + c4) = o;
  }
}

extern "C" void kernel_launch(void* const* d_in, const int* in_sizes, int n_in,
                              void* d_out, int out_size, void* d_ws, size_t ws_size,
                              hipStream_t stream) {
  const int*   tokens    = (const int*)d_in[0];    // [8,2048] int32
  const float* emb       = (const float*)d_in[1];  // [V, D]
  const float* lora_a    = (const float*)d_in[2];  // [V, R]
  const float* lora_b    = (const float*)d_in[3];  // [R, D]
  const float* magnitude = (const float*)d_in[4];  // [D]
  float* out = (float*)d_out;

  const int n_tokens = in_sizes[0];                // 16384

  float* partials = (float*)d_ws;                               // P1_BLOCKS*DIM floats (3.1 MB)
  float* scale    = (float*)d_ws + (size_t)P1_BLOCKS * DIM;     // DIM floats

  dora_pass1<<<P1_BLOCKS, P1_THREADS, 0, stream>>>(emb, lora_a, lora_b, partials);
  dora_reduce<<<RED_BLOCKS, RED_THREADS, 0, stream>>>(partials, magnitude, scale);

  const int gather_blocks = (n_tokens + TOK_PB - 1) / TOK_PB;
  dora_gather<<<gather_blocks, G_THREADS, 0, stream>>>(tokens, emb, lora_a, lora_b,
                                                       scale, out, n_tokens);
}